// Round 9
// baseline (242.421 us; speedup 1.0000x reference)
//
#include <hip/hip_runtime.h>

// LocalNetwork, ONE kernel, no intermediates:
//  block = (b, dep): recompute 3 ds planes straight from x (L3-served re-reads),
//  depth+lon conv in LDS, lat conv, write 3 contiguous output planes.
//  1280 blocks x 256 thr; single dispatch, no inter-kernel gap.

#define NELEM (15 * 64 * 128)   // 122880 floats per batch item
#define NCELL 2560              // 5*16*32

__global__ __launch_bounds__(256) void k_all(const float* __restrict__ x,
                                             const float* __restrict__ wd,
                                             const float* __restrict__ bd,
                                             const float* __restrict__ wl,
                                             const float* __restrict__ bl,
                                             const float* __restrict__ wv,
                                             const float* __restrict__ bv,
                                             float* __restrict__ out)
{
    const int b   = blockIdx.y;
    const int dep = blockIdx.x;      // [0,5)
    const int tid = threadIdx.x;     // [0,256)

    __shared__ float ds3[3 * 512];   // planes id = dep-1..dep+1 (zero outside [0,4])
    __shared__ float u_lds[512];     // lon conv output for this dep

    // ---- phase 1: downsample 3 planes directly from x ----
    const float* xb = x + (size_t)b * NELEM;
    #pragma unroll
    for (int c = tid; c < 3 * 512; c += 256) {
        const int kp = c >> 9;
        const int r  = c & 511;
        const int ih = r >> 5;
        const int iw = r & 31;
        const int id = dep - 1 + kp;
        float s = 0.f;
        if (id >= 0 && id <= 4) {
            const float* p = xb + ((size_t)(id * 3) * 64 + ih * 4) * 128 + iw * 4;
            #pragma unroll
            for (int dd = 0; dd < 3; ++dd) {
                #pragma unroll
                for (int hh = 0; hh < 4; ++hh) {
                    const float4 v = *reinterpret_cast<const float4*>(p + (dd * 64 + hh) * 128);
                    s += (v.x + v.y) + (v.z + v.w);
                }
            }
            s *= (1.f / 48.f);
        }
        ds3[c] = s;
    }
    __syncthreads();

    // ---- phase 2: u[dep][ih][iw] = lon conv at m = (dep*16+ih)*34 + iw+1 ----
    #pragma unroll
    for (int c = tid; c < 512; c += 256) {
        const int ih = c >> 5;
        const int iw = c & 31;
        const float* dsr = ds3 + ih * 32;        // kp stride = 512

        auto t1local = [&](int iwq) -> float {   // depth conv at l=(iwq*16+ih)*7+dep+1
            const int l = (iwq * 16 + ih) * 7 + dep + 1;
            const float y = wd[l * 3 + 0] * dsr[iwq]
                          + wd[l * 3 + 1] * dsr[512 + iwq]
                          + wd[l * 3 + 2] * dsr[1024 + iwq]
                          + bd[l];
            return fmaxf(y, 0.f);
        };
        auto ulon = [&](int kwq) -> float {      // lon-padded value, 0 outside [1,32]
            return (kwq >= 1 && kwq <= 32) ? t1local(kwq - 1) : 0.f;
        };

        const int kw = iw + 1;
        const int m  = (dep * 16 + ih) * 34 + kw;
        const float y = wl[m * 3 + 0] * ulon(kw - 1)
                      + wl[m * 3 + 1] * ulon(kw)
                      + wl[m * 3 + 2] * ulon(kw + 1)
                      + bl[m];
        u_lds[c] = fmaxf(y, 0.f);
    }
    __syncthreads();

    // ---- phase 3: lat conv + write 12 replicas into 3 contiguous planes ----
    float* ob = out + (size_t)b * NELEM;
    #pragma unroll
    for (int c = tid; c < 512; c += 256) {
        const int ihh = c >> 5;
        const int iww = c & 31;
        const int n   = (dep * 32 + iww) * 18 + ihh + 1;

        const float x0 = (ihh > 0)  ? u_lds[(ihh - 1) * 32 + iww] : 0.f;
        const float x1 =              u_lds[ihh * 32 + iww];
        const float x2 = (ihh < 15) ? u_lds[(ihh + 1) * 32 + iww] : 0.f;
        const float y  = fmaxf(wv[n * 3 + 0] * x0 + wv[n * 3 + 1] * x1
                             + wv[n * 3 + 2] * x2 + bv[n], 0.f);
        const float4 y4 = make_float4(y, y, y, y);

        float* pb = ob + ((size_t)(dep * 3) * 64 + ihh * 4) * 128 + iww * 4;
        #pragma unroll
        for (int dd = 0; dd < 3; ++dd) {
            #pragma unroll
            for (int hh = 0; hh < 4; ++hh) {
                *reinterpret_cast<float4*>(pb + (dd * 64 + hh) * 128) = y4;
            }
        }
    }
}

extern "C" void kernel_launch(void* const* d_in, const int* in_sizes, int n_in,
                              void* d_out, int out_size, void* d_ws, size_t ws_size,
                              hipStream_t stream) {
    const float* x       = (const float*)d_in[0];
    const float* w_depth = (const float*)d_in[1];
    const float* b_depth = (const float*)d_in[2];
    const float* w_lon   = (const float*)d_in[3];
    const float* b_lon   = (const float*)d_in[4];
    const float* w_lat   = (const float*)d_in[5];
    const float* b_lat   = (const float*)d_in[6];
    float* out = (float*)d_out;

    const int Bn = in_sizes[0] / NELEM;   // 256

    k_all<<<dim3(5, Bn), dim3(256), 0, stream>>>(x, w_depth, b_depth,
                                                 w_lon, b_lon, w_lat, b_lat, out);
}